// Round 15
// baseline (375.233 us; speedup 1.0000x reference)
//
#include <hip/hip_runtime.h>
#include <hip/hip_bf16.h>

#define BB 16
#define NN 4096
#define SS 1024
#define C1 128
#define C2 256
#define CIN 384
#define CO 128

typedef __bf16 bf16x8 __attribute__((ext_vector_type(8)));
typedef float f32x4 __attribute__((ext_vector_type(4)));

// ------- Kernel 1: 3-NN + weights, top-4 scan, tie flag --------------------
// FROZEN: byte-identical to r12/r14 (passing). -ffp-contract=fast makes FMA
// fusion backend/context-dependent; ANY edit to this kernel is a lottery.
__global__ __launch_bounds__(256) void knn_kernel(
    const float* __restrict__ xyz1, const float* __restrict__ xyz2,
    int* __restrict__ idx4, float* __restrict__ w4)
{
    __shared__ float4 pts[SS];   // x, y, z, |p|^2  -> 16 KB
    const int b = blockIdx.y;
    const float* p2 = xyz2 + (size_t)b * SS * 3;
    for (int i = threadIdx.x; i < SS; i += 256) {
        float x = p2[i * 3 + 0], y = p2[i * 3 + 1], z = p2[i * 3 + 2];
        pts[i] = make_float4(x, y, z, x * x + y * y + z * z);
    }
    __syncthreads();

    const int n = blockIdx.x * 256 + threadIdx.x;
    const float* p1 = xyz1 + ((size_t)b * NN + n) * 3;
    const float x = p1[0], y = p1[1], z = p1[2];
    const float s1 = x * x + y * y + z * z;

    float d0 = 3.4e38f, d1 = 3.4e38f, d2 = 3.4e38f, d3 = 3.4e38f;
    int i0 = 0, i1 = 0, i2 = 0, i3 = 0;
    #pragma unroll 4
    for (int s = 0; s < SS; ++s) {
        float4 p = pts[s];
        float d = s1 + p.w - 2.0f * (x * p.x + y * p.y + z * p.z);
        bool lt0 = d < d0, lt1 = d < d1, lt2 = d < d2, lt3 = d < d3;
        float nd3 = lt2 ? d2 : (lt3 ? d : d3); int ni3 = lt2 ? i2 : (lt3 ? s : i3);
        float nd2 = lt1 ? d1 : (lt2 ? d : d2); int ni2 = lt1 ? i1 : (lt2 ? s : i2);
        float nd1 = lt0 ? d0 : (lt1 ? d : d1); int ni1 = lt0 ? i0 : (lt1 ? s : i1);
        d0 = lt0 ? d : d0;                     i0 = lt0 ? s : i0;
        d1 = nd1; i1 = ni1; d2 = nd2; i2 = ni2; d3 = nd3; i3 = ni3;
    }
    float r0 = 1.0f / (d0 + 1e-8f);
    float r1 = 1.0f / (d1 + 1e-8f);
    float r2 = 1.0f / (d2 + 1e-8f);
    float rs = r0 + r1 + r2;
    bool tie = (d2 == d3);
    size_t base = ((size_t)b * NN + n) * 4;
    idx4[base + 0] = i0; idx4[base + 1] = i1;
    idx4[base + 2] = i2; idx4[base + 3] = i3;
    w4[base + 0] = r0 / rs; w4[base + 1] = r1 / rs;
    w4[base + 2] = r2 / rs; w4[base + 3] = tie ? -1.0f : 0.0f;
}

// ---- Kernel 2: points2 [C2,S] -> f32 [S,C2] + bf16 hi/lo planes [S,C2] ----
__global__ __launch_bounds__(256) void p2t_kernel(
    const float* __restrict__ p2, float* __restrict__ p2t,
    __bf16* __restrict__ p2th, __bf16* __restrict__ p2tl)
{
    __shared__ float tile[64][65];
    const int b = blockIdx.z;
    const int s0 = blockIdx.x * 64, c0 = blockIdx.y * 64;
    for (int i = threadIdx.x; i < 64 * 64; i += 256) {
        int s = i & 63, c = i >> 6;
        tile[c][s] = p2[((size_t)b * C2 + c0 + c) * SS + s0 + s];
    }
    __syncthreads();
    for (int i = threadIdx.x; i < 64 * 64; i += 256) {
        int c = i & 63, s = i >> 6;
        float v = tile[c][s];
        size_t o = ((size_t)b * SS + s0 + s) * C2 + c0 + c;
        p2t[o] = v;
        __bf16 h = (__bf16)v;
        p2th[o] = h; p2tl[o] = (__bf16)(v - (float)h);
    }
}

// ---- Kernel 2a: points1 [C1,N] -> bf16 hi/lo planes [B*N, 128] ------------
__global__ __launch_bounds__(256) void p1t_kernel(
    const float* __restrict__ points1,
    __bf16* __restrict__ P1h, __bf16* __restrict__ P1l)
{
    __shared__ float t1[128][66];
    const int b = blockIdx.y;
    const int n0 = blockIdx.x * 64;
    for (int i = threadIdx.x; i < 128 * 64; i += 256) {
        int j = i & 63, c = i >> 6;
        t1[c][j] = points1[((size_t)b * C1 + c) * NN + n0 + j];
    }
    __syncthreads();
    for (int i = threadIdx.x; i < 128 * 64; i += 256) {
        int c = i & 127, j = i >> 7;
        float v = t1[c][j];
        __bf16 h = (__bf16)v;
        size_t o = ((size_t)b * NN + n0 + j) * C1 + c;
        P1h[o] = h; P1l[o] = (__bf16)(v - (float)h);
    }
}

// ---- Kernel 2c: split weights -> hi/lo planes.  fuse_w split into
//      Wf1 = cols 0:128 (applied to P1^T) and Wf2 = cols 128:384 (-> G). ----
__global__ __launch_bounds__(256) void wprep_kernel(
    const float* __restrict__ fw, const float* __restrict__ w1,
    const float* __restrict__ w2,
    __bf16* __restrict__ Wf1h, __bf16* __restrict__ Wf1l,
    __bf16* __restrict__ Wf2h, __bf16* __restrict__ Wf2l,
    __bf16* __restrict__ W1h, __bf16* __restrict__ W1l,
    __bf16* __restrict__ W2h, __bf16* __restrict__ W2l)
{
    int t = blockIdx.x * 256 + threadIdx.x;   // 0..81919
    float v; __bf16 *oh, *ol; int idx;
    if (t < 16384) {
        int o = t >> 7, c = t & 127;
        v = fw[(size_t)o * CIN + c]; oh = Wf1h; ol = Wf1l; idx = t;
    } else if (t < 49152) {
        int t2 = t - 16384; int o = t2 >> 8, c = t2 & 255;
        v = fw[(size_t)o * CIN + 128 + c]; oh = Wf2h; ol = Wf2l; idx = t2;
    } else if (t < 65536) { idx = t - 49152; v = w1[idx]; oh = W1h; ol = W1l; }
    else                  { idx = t - 65536; v = w2[idx]; oh = W2h; ol = W2l; }
    __bf16 h = (__bf16)v;
    oh[idx] = h; ol[idx] = (__bf16)(v - (float)h);
}

// ------- Kernel 2b: tie resolver (FROZEN from r12/r14) ---------------------
__global__ __launch_bounds__(256) void tie_eval_kernel(
    const float* __restrict__ p2t, const float* __restrict__ points1,
    const int* __restrict__ idx4, float* __restrict__ w4,
    const float* __restrict__ fw, const float* __restrict__ fb,
    const float* __restrict__ fg, const float* __restrict__ fbt,
    const float* __restrict__ fm, const float* __restrict__ fv,
    const float* __restrict__ w1m, const float* __restrict__ b1,
    const float* __restrict__ g1, const float* __restrict__ bt1,
    const float* __restrict__ m1, const float* __restrict__ v1,
    const float* __restrict__ w2m, const float* __restrict__ b2,
    const float* __restrict__ g2, const float* __restrict__ bt2,
    const float* __restrict__ m2, const float* __restrict__ v2)
{
    __shared__ float Xs[4][2][CIN];
    __shared__ float XT[4][2][CO];
    __shared__ float Hs[4][2][CO];
    const int wave = threadIdx.x >> 6, lane = threadIdx.x & 63;
    const int n = blockIdx.x * 4 + wave;
    const int b = blockIdx.y;
    const size_t base = ((size_t)b * NN + n) * 4;
    if (w4[base + 3] != -1.0f) return;

    const int i0 = idx4[base + 0], i1 = idx4[base + 1];
    const int i2 = idx4[base + 2], i3 = idx4[base + 3];
    const float w0 = w4[base + 0], w1 = w4[base + 1], w2 = w4[base + 2];
    const float* P = p2t + (size_t)b * SS * C2;

    for (int c = lane; c < C1; c += 64) {
        float v = points1[((size_t)b * C1 + c) * NN + n];
        Xs[wave][0][c] = v; Xs[wave][1][c] = v;
    }
    for (int c = lane; c < C2; c += 64) {
        float f0 = P[(size_t)i0 * C2 + c], f1 = P[(size_t)i1 * C2 + c];
        float f2 = P[(size_t)i2 * C2 + c], f3 = P[(size_t)i3 * C2 + c];
        float bs = w0 * f0 + w1 * f1;
        Xs[wave][0][C1 + c] = bs + w2 * f2;
        Xs[wave][1][C1 + c] = bs + w2 * f3;
    }
    #pragma unroll
    for (int k = 0; k < 2; ++k) {
        int oc = lane + 64 * k;
        float alo = fb[oc], ahi = fb[oc];
        for (int c = 0; c < CIN; ++c) {
            float wv = fw[(size_t)oc * CIN + c];
            alo += wv * Xs[wave][0][c];
            ahi += wv * Xs[wave][1][c];
        }
        float s = fg[oc] * (1.0f / sqrtf(fv[oc] + 1e-5f));
        XT[wave][0][oc] = fmaxf(s * (alo - fm[oc]) + fbt[oc], 0.0f);
        XT[wave][1][oc] = fmaxf(s * (ahi - fm[oc]) + fbt[oc], 0.0f);
    }
    #pragma unroll
    for (int k = 0; k < 2; ++k) {
        int oc = lane + 64 * k;
        float alo = b1[oc], ahi = b1[oc];
        for (int c = 0; c < CO; ++c) {
            float wv = w1m[(size_t)oc * CO + c];
            alo += wv * XT[wave][0][c];
            ahi += wv * XT[wave][1][c];
        }
        float s = g1[oc] * (1.0f / sqrtf(v1[oc] + 1e-5f));
        Hs[wave][0][oc] = fmaxf(s * (alo - m1[oc]) + bt1[oc], 0.0f);
        Hs[wave][1][oc] = fmaxf(s * (ahi - m1[oc]) + bt1[oc], 0.0f);
    }
    float e = 0.0f;
    #pragma unroll
    for (int k = 0; k < 2; ++k) {
        int oc = lane + 64 * k;
        float alo = b2[oc], ahi = b2[oc];
        for (int c = 0; c < CO; ++c) {
            float wv = w2m[(size_t)oc * CO + c];
            alo += wv * Hs[wave][0][c];
            ahi += wv * Hs[wave][1][c];
        }
        float s = g2[oc] * (1.0f / sqrtf(v2[oc] + 1e-5f));
        float olo = fmaxf(s * (alo - m2[oc]) + bt2[oc] + XT[wave][0][oc], 0.0f);
        float ohi = fmaxf(s * (ahi - m2[oc]) + bt2[oc] + XT[wave][1][oc], 0.0f);
        e = fmaxf(e, fabsf(olo - ohi));
    }
    for (int off = 32; off; off >>= 1) e = fmaxf(e, __shfl_xor(e, off));
    if (lane == 0) {
        if (e > 0.085f) { w4[base + 3] = 0.0f; }
        else { w4[base + 2] = 0.5f * w2; w4[base + 3] = 0.5f * w2; }
    }
}

// ------- GEMM template ------------------------------------------------------
// MODE 0: relu(bn(A@W^T+cb))                 -> bf16 hi/lo planes
// MODE 1: relu(bn(A@W^T+cb)+skip)            -> f32 transposed [B,128,N]
// MODE 2: A@W^T raw                          -> f32 [M,128]      (G build)
// MODE 3: relu(bn(A@W^T + Igather + cb))     -> bf16 hi/lo planes (fuse)
template<int K, int MODE>
__global__ __launch_bounds__(256) void gemm_bn_kernel(
    const __bf16* __restrict__ Ah, const __bf16* __restrict__ Al,
    const __bf16* __restrict__ Wh, const __bf16* __restrict__ Wl,
    const float* __restrict__ cb,  const float* __restrict__ gg,
    const float* __restrict__ bbta, const float* __restrict__ mm,
    const float* __restrict__ vv,
    const __bf16* __restrict__ skiph, const __bf16* __restrict__ skipl,
    const float* __restrict__ Gg, const int* __restrict__ idx4,
    const float* __restrict__ w4,
    __bf16* __restrict__ outh, __bf16* __restrict__ outl,
    float* __restrict__ outf)
{
    __shared__ __attribute__((aligned(16))) __bf16 wls_h[128 * 40];
    __shared__ __attribute__((aligned(16))) __bf16 wls_l[128 * 40];
    __shared__ float s_s[128], s_t[128];
    __shared__ float tile[(MODE == 1) ? 32 : 1][132];
    __shared__ float Itile[(MODE == 3) ? 128 : 1][129];
    const int tid = threadIdx.x;
    if (MODE != 2 && tid < 128) {
        float s = gg[tid] * (1.0f / sqrtf(vv[tid] + 1e-5f));
        float t = (cb[tid] - mm[tid]) * s + bbta[tid];
        s_s[tid] = s; s_t[tid] = t;
    }
    if (MODE == 3) {   // gather Σ w_k G[idx_k] into Itile (coalesced rows)
        const size_t gr = (size_t)blockIdx.x * 128;
        const int bb = (int)(gr >> 12);
        const float* Gb = Gg + (size_t)bb * SS * 128;
        for (int it = 0; it < 64; ++it) {
            int i = it * 256 + tid;
            int qq = i >> 7, c = i & 127;
            size_t ib = (gr + qq) * 4;
            int j0 = idx4[ib + 0], j1 = idx4[ib + 1];
            int j2 = idx4[ib + 2], j3 = idx4[ib + 3];
            float u0 = w4[ib + 0], u1 = w4[ib + 1];
            float u2 = w4[ib + 2], u3 = w4[ib + 3];
            Itile[qq][c] = u0 * Gb[(size_t)j0 * 128 + c]
                         + u1 * Gb[(size_t)j1 * 128 + c]
                         + u2 * Gb[(size_t)j2 * 128 + c]
                         + u3 * Gb[(size_t)j3 * 128 + c];
        }
    }
    const int wave = tid >> 6, lane = tid & 63;
    const int m = lane & 15, q = lane >> 4;
    const size_t r0 = (size_t)blockIdx.x * 128 + wave * 32;

    f32x4 acc[2][8] = {};
    const __bf16* pAh = Ah + (r0 + m) * (size_t)K + q * 8;
    const __bf16* pAl = Al + (r0 + m) * (size_t)K + q * 8;

    const int wrow = tid >> 1, whf = tid & 1;
    for (int kk = 0; kk < K; kk += 32) {
        __syncthreads();
        {
            size_t g = (size_t)wrow * K + kk + whf * 16;
            int lo = wrow * 40 + whf * 16;
            *(uint4*)&wls_h[lo]     = *(const uint4*)&Wh[g];
            *(uint4*)&wls_h[lo + 8] = *(const uint4*)&Wh[g + 8];
            *(uint4*)&wls_l[lo]     = *(const uint4*)&Wl[g];
            *(uint4*)&wls_l[lo + 8] = *(const uint4*)&Wl[g + 8];
        }
        __syncthreads();
        bf16x8 ah0 = *(const bf16x8*)(pAh + kk);
        bf16x8 al0 = *(const bf16x8*)(pAl + kk);
        bf16x8 ah1 = *(const bf16x8*)(pAh + 16 * (size_t)K + kk);
        bf16x8 al1 = *(const bf16x8*)(pAl + 16 * (size_t)K + kk);
        #pragma unroll
        for (int ot = 0; ot < 8; ++ot) {
            bf16x8 bh = *(const bf16x8*)&wls_h[(ot * 16 + m) * 40 + q * 8];
            bf16x8 bl = *(const bf16x8*)&wls_l[(ot * 16 + m) * 40 + q * 8];
            acc[0][ot] = __builtin_amdgcn_mfma_f32_16x16x32_bf16(ah0, bh, acc[0][ot], 0, 0, 0);
            acc[0][ot] = __builtin_amdgcn_mfma_f32_16x16x32_bf16(al0, bh, acc[0][ot], 0, 0, 0);
            acc[0][ot] = __builtin_amdgcn_mfma_f32_16x16x32_bf16(ah0, bl, acc[0][ot], 0, 0, 0);
            acc[1][ot] = __builtin_amdgcn_mfma_f32_16x16x32_bf16(ah1, bh, acc[1][ot], 0, 0, 0);
            acc[1][ot] = __builtin_amdgcn_mfma_f32_16x16x32_bf16(al1, bh, acc[1][ot], 0, 0, 0);
            acc[1][ot] = __builtin_amdgcn_mfma_f32_16x16x32_bf16(ah1, bl, acc[1][ot], 0, 0, 0);
        }
    }

    if (MODE == 0 || MODE == 3) {
        #pragma unroll
        for (int rt = 0; rt < 2; ++rt) {
            #pragma unroll
            for (int ot = 0; ot < 8; ++ot) {
                int col = ot * 16 + m;
                float sc = s_s[col], sh = s_t[col];
                #pragma unroll
                for (int r = 0; r < 4; ++r) {
                    int lrow = wave * 32 + rt * 16 + q * 4 + r;
                    size_t row = (size_t)blockIdx.x * 128 + lrow;
                    float a = acc[rt][ot][r];
                    if (MODE == 3) a += Itile[lrow][col];
                    float val = fmaxf(a * sc + sh, 0.0f);
                    __bf16 h = (__bf16)val;
                    outh[row * 128 + col] = h;
                    outl[row * 128 + col] = (__bf16)(val - (float)h);
                }
            }
        }
    } else if (MODE == 2) {
        #pragma unroll
        for (int rt = 0; rt < 2; ++rt) {
            #pragma unroll
            for (int ot = 0; ot < 8; ++ot) {
                int col = ot * 16 + m;
                #pragma unroll
                for (int r = 0; r < 4; ++r) {
                    size_t row = r0 + rt * 16 + q * 4 + r;
                    outf[row * 128 + col] = acc[rt][ot][r];
                }
            }
        }
    } else {
        const int bidx = (int)(((size_t)blockIdx.x * 128) >> 12);
        const int nbase = (int)(((size_t)blockIdx.x * 128) & 4095);
        for (int cc = 0; cc < 4; ++cc) {
            __syncthreads();
            #pragma unroll
            for (int oo = 0; oo < 2; ++oo) {
                int ot = cc * 2 + oo;
                int col = ot * 16 + m;
                float sc = s_s[col], sh = s_t[col];
                #pragma unroll
                for (int rt = 0; rt < 2; ++rt) {
                    #pragma unroll
                    for (int r = 0; r < 4; ++r) {
                        int lrow = wave * 32 + rt * 16 + q * 4 + r;
                        size_t row = (size_t)blockIdx.x * 128 + lrow;
                        float val = acc[rt][ot][r] * sc + sh;
                        val += (float)skiph[row * 128 + col] + (float)skipl[row * 128 + col];
                        val = fmaxf(val, 0.0f);
                        tile[oo * 16 + m][lrow] = val;
                    }
                }
            }
            __syncthreads();
            for (int c2 = tid >> 7; c2 < 32; c2 += 2) {
                int nn_ = tid & 127;
                outf[((size_t)bidx * 128 + cc * 32 + c2) * NN + nbase + nn_] = tile[c2][nn_];
            }
        }
    }
}

extern "C" void kernel_launch(void* const* d_in, const int* in_sizes, int n_in,
                              void* d_out, int out_size, void* d_ws, size_t ws_size,
                              hipStream_t stream) {
    const float* xyz1    = (const float*)d_in[0];
    const float* xyz2    = (const float*)d_in[1];
    const float* points1 = (const float*)d_in[2];
    const float* points2 = (const float*)d_in[3];
    const float* fuse_w  = (const float*)d_in[4];
    const float* fuse_b  = (const float*)d_in[5];
    const float* fuse_g  = (const float*)d_in[6];
    const float* fuse_bt = (const float*)d_in[7];
    const float* fuse_m  = (const float*)d_in[8];
    const float* fuse_v  = (const float*)d_in[9];
    const float* c1_w    = (const float*)d_in[10];
    const float* c1_b    = (const float*)d_in[11];
    const float* bn1_g   = (const float*)d_in[12];
    const float* bn1_b   = (const float*)d_in[13];
    const float* bn1_m   = (const float*)d_in[14];
    const float* bn1_v   = (const float*)d_in[15];
    const float* c2_w    = (const float*)d_in[16];
    const float* c2_b    = (const float*)d_in[17];
    const float* bn2_g   = (const float*)d_in[18];
    const float* bn2_b   = (const float*)d_in[19];
    const float* bn2_m   = (const float*)d_in[20];
    const float* bn2_v   = (const float*)d_in[21];

    char* ws = (char*)d_ws;
    int*    idx4 = (int*)(ws);                      // 1 MB
    float*  w4   = (float*)(ws + 1048576);          // 1 MB
    float*  p2t  = (float*)(ws + 2097152);          // 16.78 MB
    __bf16* p2th = (__bf16*)(ws + 18874368);        // 8.39 MB
    __bf16* p2tl = (__bf16*)(ws + 27262976);        // 8.39 MB
    __bf16* P1h  = (__bf16*)(ws + 35651584);        // 16.78 MB
    __bf16* P1l  = (__bf16*)(ws + 52428800);        // 16.78 MB
    float*  G    = (float*)(ws + 69206016);         // 8.39 MB
    __bf16* Y0h  = (__bf16*)(ws + 77594624);        // 16.78 MB
    __bf16* Y0l  = (__bf16*)(ws + 94371840);        // 16.78 MB
    __bf16* Hh   = (__bf16*)(ws + 111149056);       // 16.78 MB
    __bf16* Hl   = (__bf16*)(ws + 127926272);       // 16.78 MB
    __bf16* Wf1h = (__bf16*)(ws + 144703488);       // 32 KB
    __bf16* Wf1l = (__bf16*)(ws + 144736256);       // 32 KB
    __bf16* Wf2h = (__bf16*)(ws + 144769024);       // 64 KB
    __bf16* Wf2l = (__bf16*)(ws + 144834560);       // 64 KB
    __bf16* W1h  = (__bf16*)(ws + 144900096);       // 32 KB
    __bf16* W1l  = (__bf16*)(ws + 144932864);       // 32 KB
    __bf16* W2h  = (__bf16*)(ws + 144965632);       // 32 KB
    __bf16* W2l  = (__bf16*)(ws + 144998400);       // 32 KB

    knn_kernel<<<dim3(NN / 256, BB), 256, 0, stream>>>(xyz1, xyz2, idx4, w4);
    p2t_kernel<<<dim3(SS / 64, C2 / 64, BB), 256, 0, stream>>>(points2, p2t, p2th, p2tl);
    p1t_kernel<<<dim3(NN / 64, BB), 256, 0, stream>>>(points1, P1h, P1l);
    wprep_kernel<<<320, 256, 0, stream>>>(fuse_w, c1_w, c2_w,
                                          Wf1h, Wf1l, Wf2h, Wf2l,
                                          W1h, W1l, W2h, W2l);
    tie_eval_kernel<<<dim3(NN / 4, BB), 256, 0, stream>>>(
        p2t, points1, idx4, w4,
        fuse_w, fuse_b, fuse_g, fuse_bt, fuse_m, fuse_v,
        c1_w, c1_b, bn1_g, bn1_b, bn1_m, bn1_v,
        c2_w, c2_b, bn2_g, bn2_b, bn2_m, bn2_v);

    // G = P2^T @ Wf2^T   [B*S, 128] f32
    gemm_bn_kernel<C2, 2><<<(BB * SS) / 128, 256, 0, stream>>>(
        p2th, p2tl, Wf2h, Wf2l, fuse_b, fuse_g, fuse_bt, fuse_m, fuse_v,
        nullptr, nullptr, nullptr, nullptr, nullptr, nullptr, nullptr, G);
    // Y0 = relu(bn(P1^T @ Wf1^T + Σ w_k G[idx_k] + cb))
    gemm_bn_kernel<C1, 3><<<(BB * NN) / 128, 256, 0, stream>>>(
        P1h, P1l, Wf1h, Wf1l, fuse_b, fuse_g, fuse_bt, fuse_m, fuse_v,
        nullptr, nullptr, G, idx4, w4, Y0h, Y0l, nullptr);
    // H = relu(bn1(Y0 @ W1^T + b1))
    gemm_bn_kernel<CO, 0><<<(BB * NN) / 128, 256, 0, stream>>>(
        Y0h, Y0l, W1h, W1l, c1_b, bn1_g, bn1_b, bn1_m, bn1_v,
        nullptr, nullptr, nullptr, nullptr, nullptr, Hh, Hl, nullptr);
    // out = relu(bn2(H @ W2^T + b2) + Y0), transposed store
    gemm_bn_kernel<CO, 1><<<(BB * NN) / 128, 256, 0, stream>>>(
        Hh, Hl, W2h, W2l, c2_b, bn2_g, bn2_b, bn2_m, bn2_v,
        Y0h, Y0l, nullptr, nullptr, nullptr, nullptr, nullptr, (float*)d_out);
}